// Round 10
// baseline (165.609 us; speedup 1.0000x reference)
//
#include <hip/hip_runtime.h>
#include <hip/hip_bf16.h>

typedef __attribute__((ext_vector_type(8))) short bf16x8;
typedef __attribute__((ext_vector_type(4))) float f32x4;

#define B_  512
#define N_  256
#define SD_ 1024
#define HD_ 512
#define AD_ 256

__device__ __forceinline__ unsigned short f2bf(float f) {
    unsigned int u = __float_as_uint(f);
    unsigned int r = (u + 0x7FFFu + ((u >> 16) & 1u)) >> 16;
    return (unsigned short)r;
}

// ---------------------------------------------------------------------------
// K0: pack Wh (AD x HD, f32, row-major) into bf16 B-fragment layout for
// mfma_f32_16x16x32_bf16. Fragment (ct, ks): 64 lanes x 8 bf16 contiguous.
__global__ void k0_pack(const float* __restrict__ Wh, unsigned short* __restrict__ whp) {
    int g = blockIdx.x * 256 + threadIdx.x;
    int ct  = g >> 10;
    int rem = g & 1023;
    int ks  = rem >> 6;
    int l   = rem & 63;
    int a   = ct * 16 + (l & 15);
    int kb  = ks * 32 + (l >> 4) * 8;
    const float* src = Wh + (size_t)a * HD_ + kb;
    float4 v0 = *(const float4*)(src);
    float4 v1 = *(const float4*)(src + 4);
    bf16x8 o;
    o[0] = (short)f2bf(v0.x); o[1] = (short)f2bf(v0.y);
    o[2] = (short)f2bf(v0.z); o[3] = (short)f2bf(v0.w);
    o[4] = (short)f2bf(v1.x); o[5] = (short)f2bf(v1.y);
    o[6] = (short)f2bf(v1.z); o[7] = (short)f2bf(v1.w);
    ((bf16x8*)whp)[g] = o;
}

// ---------------------------------------------------------------------------
// K1: 2 b's per block, 512 threads. sp = state@Ws^T + bs (coalesced Ws reads),
// sn = max(||sp||,eps).
__global__ __launch_bounds__(512) void k1_proj(
    const float* __restrict__ state, const float* __restrict__ Ws,
    const float* __restrict__ bs,
    float* __restrict__ sn, float* __restrict__ spv)
{
    __shared__ float st[2][SD_];
    __shared__ float spl[2][AD_];
    __shared__ float red[2][AD_];
    int tid = threadIdx.x, lane = tid & 63, w = tid >> 6;
    int b0 = blockIdx.x * 2;
    ((float4*)st)[tid] = ((const float4*)(state + (size_t)b0 * SD_))[tid];
    __syncthreads();
    float4 s0[4], s1[4];
    #pragma unroll
    for (int seg = 0; seg < 4; ++seg) {
        s0[seg] = *(const float4*)&st[0][seg * 256 + lane * 4];
        s1[seg] = *(const float4*)&st[1][seg * 256 + lane * 4];
    }
    #pragma unroll 2
    for (int i = 0; i < 32; ++i) {
        int a = w * 32 + i;
        const float4* wr = (const float4*)(Ws + (size_t)a * SD_);
        float p0 = 0.f, p1 = 0.f;
        #pragma unroll
        for (int seg = 0; seg < 4; ++seg) {
            float4 wv = wr[seg * 64 + lane];
            p0 += wv.x * s0[seg].x + wv.y * s0[seg].y + wv.z * s0[seg].z + wv.w * s0[seg].w;
            p1 += wv.x * s1[seg].x + wv.y * s1[seg].y + wv.z * s1[seg].z + wv.w * s1[seg].w;
        }
        #pragma unroll
        for (int d = 1; d < 64; d <<= 1) { p0 += __shfl_xor(p0, d); p1 += __shfl_xor(p1, d); }
        if (lane == 0) {
            float bsa = bs[a];
            spl[0][a] = p0 + bsa;
            spl[1][a] = p1 + bsa;
        }
    }
    __syncthreads();
    int tb = tid >> 8, t = tid & 255;
    float sv = spl[tb][t];
    spv[(size_t)(b0 + tb) * AD_ + t] = sv;
    red[tb][t] = sv * sv;
    __syncthreads();
    for (int s = 128; s > 0; s >>= 1) { if (t < s) red[tb][t] += red[tb][t + s]; __syncthreads(); }
    if (t == 0) sn[b0 + tb] = fmaxf(sqrtf(red[tb][0]), 1e-8f);
}

// ---------------------------------------------------------------------------
// K2 fused: one block per b (512 threads, 8 waves), 2 blocks/CU.
// CONTIGUITY RESTRUCTURE (R9 lesson: 512B-fragment phases -> 1.7TB/s DRAM
// thrash): per mc, stage the FULL 64x512 f32 slab (each thread 256B
// contiguous; each wave 8 complete 2KB rows) into one 64KB bf16 LDS tile,
// then sweep all K=512 MFMA from LDS with no intra-K barriers (2 barriers/mc,
// 8 total). The 2 blocks/CU anti-phase: one stages while the other computes
// (m114 wave-level overlap). Swizzle slot^(row&15): uniform 8-lanes-per-bank-
// class on both ds_write_b128 and ds_read_b128 (optimal).
__global__ __launch_bounds__(512, 2) void k2_fused(
    const float* __restrict__ hints, const unsigned short* __restrict__ whp,
    const float* __restrict__ spv, const float* __restrict__ sn,
    const float* __restrict__ bh, float* __restrict__ out)
{
    __shared__ __align__(16) char smem[74752];
    unsigned short* tile = (unsigned short*)smem;             // 64KB [64][512] bf16 swizzled
    float* sp_lds  = (float*)(smem + 65536);                  // 1KB
    float* bh_lds  = (float*)(smem + 66560);                  // 1KB
    float* norm2p  = (float*)(smem + 67584);                  // 2KB
    float* nump    = (float*)(smem + 69632);                  // 2KB
    float* sc      = (float*)(smem + 71680);                  // 1KB
    float* red     = (float*)(smem + 72704);                  // 1KB
    float* wsm     = (float*)(smem + 73728);                  // 1KB
    float* scratch = (float*)smem;                            // epilogue alias

    int tid = threadIdx.x, lane = tid & 63, w = tid >> 6;
    int b = blockIdx.x;
    const float* hb = hints + (size_t)b * N_ * HD_;
    if (tid < 64) ((float4*)sp_lds)[tid] = ((const float4*)(spv + (size_t)b * AD_))[tid];
    else if (tid < 128) ((float4*)bh_lds)[tid - 64] = ((const float4*)bh)[tid - 64];
    float snb = sn[b];
    int cl = lane & 15;
    int srow = tid >> 3;      // staging row 0..63
    int sseg = tid & 7;       // 64-f32 segment within the row
    const float* srcrow = hb + (size_t)srow * HD_ + sseg * 64;
    __syncthreads();
    float bh0 = bh_lds[(2 * w + 0) * 16 + cl];
    float bh1 = bh_lds[(2 * w + 1) * 16 + cl];
    float sp0 = sp_lds[(2 * w + 0) * 16 + cl];
    float sp1 = sp_lds[(2 * w + 1) * 16 + cl];

    #pragma unroll 1
    for (int mc = 0; mc < 4; ++mc) {
        // ---- stage: 64 rows x 512 f32 -> bf16 tile (contiguous HBM reads)
        const float* src = srcrow + (size_t)(mc * 64) * HD_;
        #pragma unroll
        for (int h = 0; h < 2; ++h) {
            float4 v[8];
            #pragma unroll
            for (int j = 0; j < 8; ++j)
                v[j] = *(const float4*)(src + h * 32 + j * 4);
            #pragma unroll
            for (int j2 = 0; j2 < 4; ++j2) {
                int s = sseg * 8 + h * 4 + j2;
                int sw = s ^ (srow & 15);
                float4 a = v[2 * j2], c = v[2 * j2 + 1];
                bf16x8 pk;
                pk[0] = (short)f2bf(a.x); pk[1] = (short)f2bf(a.y);
                pk[2] = (short)f2bf(a.z); pk[3] = (short)f2bf(a.w);
                pk[4] = (short)f2bf(c.x); pk[5] = (short)f2bf(c.y);
                pk[6] = (short)f2bf(c.z); pk[7] = (short)f2bf(c.w);
                *(bf16x8*)((char*)tile + srow * 1024 + sw * 16) = pk;
            }
        }
        __syncthreads();

        // ---- MFMA sweep: all K=512 from LDS, no barriers
        f32x4 acc[4][2];
        #pragma unroll
        for (int mf = 0; mf < 4; ++mf) {
            acc[mf][0] = (f32x4){0.f, 0.f, 0.f, 0.f};
            acc[mf][1] = (f32x4){0.f, 0.f, 0.f, 0.f};
        }
        #pragma unroll
        for (int kidx = 0; kidx < 16; ++kidx) {
            bf16x8 bfr0 = ((const bf16x8*)whp)[((2 * w + 0) * 16 + kidx) * 64 + lane];
            bf16x8 bfr1 = ((const bf16x8*)whp)[((2 * w + 1) * 16 + kidx) * 64 + lane];
            #pragma unroll
            for (int mf = 0; mf < 4; ++mf) {
                int r = mf * 16 + cl;
                int s = kidx * 4 + (lane >> 4);
                bf16x8 afr = *(const bf16x8*)((const char*)tile + r * 1024 +
                                              ((s ^ (r & 15)) << 4));
                acc[mf][0] = __builtin_amdgcn_mfma_f32_16x16x32_bf16(afr, bfr0, acc[mf][0], 0, 0, 0);
                acc[mf][1] = __builtin_amdgcn_mfma_f32_16x16x32_bf16(afr, bfr1, acc[mf][1], 0, 0, 0);
            }
        }

        // ---- norm2 + numerator. C layout: col = ct*16+cl, row = mf*16+(lane>>4)*4+r
        #pragma unroll
        for (int mf = 0; mf < 4; ++mf) {
            #pragma unroll
            for (int r = 0; r < 4; ++r) {
                float h0 = acc[mf][0][r] + bh0;
                float h1 = acc[mf][1][r] + bh1;
                float vv = h0 * h0 + h1 * h1;
                float uu = sp0 * h0 + sp1 * h1;
                vv += __shfl_xor(vv, 1); uu += __shfl_xor(uu, 1);
                vv += __shfl_xor(vv, 2); uu += __shfl_xor(uu, 2);
                vv += __shfl_xor(vv, 4); uu += __shfl_xor(uu, 4);
                vv += __shfl_xor(vv, 8); uu += __shfl_xor(uu, 8);
                if (cl == 0) {
                    int idx = w * 64 + mf * 16 + (lane >> 4) * 4 + r;
                    norm2p[idx] = vv;
                    nump[idx]   = uu;
                }
            }
        }
        __syncthreads();
        if (tid < 64) {
            float n2 = 0.f, nm = 0.f;
            #pragma unroll
            for (int ww = 0; ww < 8; ++ww) {
                n2 += norm2p[ww * 64 + tid];
                nm += nump[ww * 64 + tid];
            }
            float hn = fmaxf(sqrtf(n2), 1e-8f);
            sc[mc * 64 + tid] = nm / (snb * hn);
        }
        // no barrier needed: next stage touches tile only; norm2p/nump are
        // re-written only after the next stage's __syncthreads.
    }
    __syncthreads();

    // softmax over sc[256]
    if (tid < 256) red[tid] = sc[tid];
    __syncthreads();
    for (int s = 128; s > 0; s >>= 1) { if (tid < s) red[tid] = fmaxf(red[tid], red[tid + s]); __syncthreads(); }
    float mx = red[0];
    __syncthreads();
    if (tid < 256) { float e = __expf(sc[tid] - mx); sc[tid] = e; red[tid] = e; }
    __syncthreads();
    for (int s = 128; s > 0; s >>= 1) { if (tid < s) red[tid] += red[tid + s]; __syncthreads(); }
    float inv = 1.f / red[0];
    __syncthreads();
    if (tid < 256) wsm[tid] = sc[tid] * inv;
    __syncthreads();

    // weighted sum (vectorized): 4 n-groups x 128 h-groups, then LDS combine
    int hg = tid & 127, ng = tid >> 7;
    const float* hbe = hb + (size_t)(ng * 64) * HD_ + hg * 4;
    float ax = 0.f, ay = 0.f, az = 0.f, aw = 0.f;
    #pragma unroll 8
    for (int n = 0; n < 64; ++n) {
        float4 hv = *(const float4*)(hbe + (size_t)n * HD_);
        float wn = wsm[ng * 64 + n];
        ax += wn * hv.x; ay += wn * hv.y; az += wn * hv.z; aw += wn * hv.w;
    }
    *(float4*)(scratch + ng * 512 + hg * 4) = (float4){ax, ay, az, aw};
    __syncthreads();
    out[(size_t)b * HD_ + tid] =
        scratch[tid] + scratch[512 + tid] + scratch[1024 + tid] + scratch[1536 + tid];
}

// ---------------------------------------------------------------------------
extern "C" void kernel_launch(void* const* d_in, const int* in_sizes, int n_in,
                              void* d_out, int out_size, void* d_ws, size_t ws_size,
                              hipStream_t stream) {
    const float* state = (const float*)d_in[0];
    const float* hints = (const float*)d_in[1];
    const float* Ws    = (const float*)d_in[2];
    const float* bs    = (const float*)d_in[3];
    const float* Wh    = (const float*)d_in[4];
    const float* bh    = (const float*)d_in[5];
    float* out = (float*)d_out;

    float* sn = (float*)d_ws;                              // B
    float* spv = sn + B_;                                  // B*AD
    unsigned short* whp = (unsigned short*)(spv + (size_t)B_ * AD_);  // AD*HD bf16

    k0_pack<<<64, 256, 0, stream>>>(Wh, whp);
    k1_proj<<<B_ / 2, 512, 0, stream>>>(state, Ws, bs, sn, spv);
    k2_fused<<<B_, 512, 0, stream>>>(hints, whp, spv, sn, bh, out);
}